// Round 1
// baseline (855.429 us; speedup 1.0000x reference)
//
#include <hip/hip_runtime.h>

#define B_ 16
#define T_ 128
#define H_ 512
#define V_ 50257
#define VP_ 50304            // 393*128 (padded V)
#define NBLK 393             // VP_/128
#define M_ (B_*T_)           // 2048 rows (t*16+b)
#define N4H 2048             // 4*H
#define KH 512               // K of hidden GEMMs
#define NKB 16               // KH/32
#define FP_ 32               // flag pad (ints) = 128 B per flag line
#define NTILES (NBLK * 16)   // 6288 logits tiles
#define NWORK 224            // logits worker blocks (32..255)
#define NCHUNK (VP_ * 16 / 16)  // 50304 SWP pack chunks
#define HP_ 536              // LDS h pitch (ushorts): 1072 B, 16B-aligned, conflict-benign

typedef __attribute__((ext_vector_type(8))) short short8;   // bf16x8 frag
typedef __attribute__((ext_vector_type(4))) float floatx4;
typedef __attribute__((ext_vector_type(4))) unsigned int u32x4;
typedef unsigned long long u64;
typedef unsigned int u32;

static __device__ __forceinline__ unsigned short f2bf(float f) {
    unsigned int u = __builtin_bit_cast(unsigned int, f);
    unsigned int r = (u + 0x7FFFu + ((u >> 16) & 1u)) >> 16;
    return (unsigned short)r;
}
// write-through stores, visible at IC (producers only)
static __device__ __forceinline__ void st_ic(u64* p, u64 v) {
    __hip_atomic_store(p, v, __ATOMIC_RELAXED, __HIP_MEMORY_SCOPE_AGENT);
}
static __device__ __forceinline__ void st_ic32(u32* p, u32 v) {
    __hip_atomic_store(p, v, __ATOMIC_RELAXED, __HIP_MEMORY_SCOPE_AGENT);
}

// ---- tagged-poll: coherent (L1/L2-bypass) 64B load; tag match == data ready ----
// The poll load IS the data load: one L3 round trip replaces (ack + flag + flag-poll + load).
static __device__ __forceinline__ void poll16(const u32* p, u32 tag, u32* v) {
    u32x4 a0, a1, a2, a3;
    while (true) {
        asm volatile(
            "global_load_dwordx4 %0, %4, off sc0 sc1\n\t"
            "global_load_dwordx4 %1, %4, off offset:16 sc0 sc1\n\t"
            "global_load_dwordx4 %2, %4, off offset:32 sc0 sc1\n\t"
            "global_load_dwordx4 %3, %4, off offset:48 sc0 sc1\n\t"
            "s_waitcnt vmcnt(0)"
            : "=&v"(a0), "=&v"(a1), "=&v"(a2), "=&v"(a3)
            : "v"(p)
            : "memory");
        u32 bad = 0;
#pragma unroll
        for (int j = 0; j < 4; ++j)
            bad |= ((a0[j] ^ tag) & 0xffffu) | ((a1[j] ^ tag) & 0xffffu) |
                   ((a2[j] ^ tag) & 0xffffu) | ((a3[j] ^ tag) & 0xffffu);
        if (bad == 0) break;
        __builtin_amdgcn_s_sleep(1);
    }
#pragma unroll
    for (int j = 0; j < 4; ++j) { v[j] = a0[j]; v[4+j] = a1[j]; v[8+j] = a2[j]; v[12+j] = a3[j]; }
}

static __device__ __forceinline__ void poll2(const u32* p1, u32 tag1,
                                             const u32* p2, u32 tag2,
                                             u32* v1, u32* v2) {
    u32x4 a0, a1, a2, a3, b0, b1, b2, b3;
    while (true) {
        asm volatile(
            "global_load_dwordx4 %0, %8, off sc0 sc1\n\t"
            "global_load_dwordx4 %1, %8, off offset:16 sc0 sc1\n\t"
            "global_load_dwordx4 %2, %8, off offset:32 sc0 sc1\n\t"
            "global_load_dwordx4 %3, %8, off offset:48 sc0 sc1\n\t"
            "global_load_dwordx4 %4, %9, off sc0 sc1\n\t"
            "global_load_dwordx4 %5, %9, off offset:16 sc0 sc1\n\t"
            "global_load_dwordx4 %6, %9, off offset:32 sc0 sc1\n\t"
            "global_load_dwordx4 %7, %9, off offset:48 sc0 sc1\n\t"
            "s_waitcnt vmcnt(0)"
            : "=&v"(a0), "=&v"(a1), "=&v"(a2), "=&v"(a3),
              "=&v"(b0), "=&v"(b1), "=&v"(b2), "=&v"(b3)
            : "v"(p1), "v"(p2)
            : "memory");
        u32 bad = 0;
#pragma unroll
        for (int j = 0; j < 4; ++j) {
            bad |= ((a0[j] ^ tag1) & 0xffffu) | ((a1[j] ^ tag1) & 0xffffu) |
                   ((a2[j] ^ tag1) & 0xffffu) | ((a3[j] ^ tag1) & 0xffffu);
            bad |= ((b0[j] ^ tag2) & 0xffffu) | ((b1[j] ^ tag2) & 0xffffu) |
                   ((b2[j] ^ tag2) & 0xffffu) | ((b3[j] ^ tag2) & 0xffffu);
        }
        if (bad == 0) break;
        __builtin_amdgcn_s_sleep(1);
    }
#pragma unroll
    for (int j = 0; j < 4; ++j) {
        v1[j] = a0[j]; v1[4+j] = a1[j]; v1[8+j] = a2[j]; v1[12+j] = a3[j];
        v2[j] = b0[j]; v2[4+j] = b1[j]; v2[8+j] = b2[j]; v2[12+j] = b3[j];
    }
}

// strip tags, pack to bf16, stage row-major [16][512] slice into LDS
static __device__ __forceinline__ void stage_row(unsigned short* hs, int tid, const u32* v) {
    int b = tid >> 5, c0 = (tid & 31) << 4;
    u32x4 w0, w1;
#pragma unroll
    for (int i = 0; i < 4; ++i) w0[i] = (v[2*i]   >> 16) | (v[2*i+1]   & 0xffff0000u);
#pragma unroll
    for (int i = 0; i < 4; ++i) w1[i] = (v[8+2*i] >> 16) | (v[8+2*i+1] & 0xffff0000u);
    *(u32x4*)(hs + (size_t)b * HP_ + c0)     = w0;
    *(u32x4*)(hs + (size_t)b * HP_ + c0 + 8) = w1;
}

// ---------------- merged setup: embed gather + W1x pack + stream zero + misc init ----------------
__global__ void k_setup(const int* __restrict__ tokens, const int* __restrict__ labels,
                        const float* __restrict__ emb, const float* __restrict__ W1,
                        unsigned short* __restrict__ X, unsigned short* __restrict__ W1xP,
                        u32* __restrict__ T1, u32* __restrict__ T2,
                        int* __restrict__ lab_r, int* __restrict__ flags) {
    int blk = blockIdx.x, t = threadIdx.x;
    if (blk < 4096) {
        // embedding gather -> bf16 X [T*B, H] (row = t*16+b)
        int tid = blk * 256 + t;           // 1,048,576 = M_*H_
        int row = tid >> 9, col = tid & 511;
        int tt = row >> 4, b = row & 15;
        int tok = tokens[b * T_ + tt];
        X[tid] = f2bf(emb[(size_t)tok * H_ + col]);
    } else if (blk < 4608) {
        // pack x-part of W1 (rows 0..511) into MFMA B-frag order
        int chunk = (blk - 4096) * 4 + (t >> 6);   // 2048 chunks
        int lane = t & 63;
        int nt = chunk >> 4, kb = chunk & 15;
        int n = nt * 16 + (lane & 15);
        int k = kb * 32 + ((lane >> 4) << 3);
        unsigned short vals[8];
#pragma unroll
        for (int j = 0; j < 8; ++j) vals[j] = f2bf(W1[(size_t)(k + j) * N4H + n]);
        *(short8*)(W1xP + (size_t)chunk * 512 + lane * 8) = *(short8*)vals;
    } else if (blk < 5120) {
        // zero tagged h1 stream (tag 0 == invalid); kernel-boundary flush makes it L3-visible
        u32x4 z = (u32x4){0, 0, 0, 0};
        u32x4* p = (u32x4*)T1 + (size_t)(blk - 4608) * 512 + t * 2;
        p[0] = z; p[1] = z;
    } else if (blk < 5128) {
        // zero tagged h2 ring (2 slots)
        u32x4 z = (u32x4){0, 0, 0, 0};
        u32x4* p = (u32x4*)T2 + (size_t)(blk - 5120) * 512 + t * 2;
        p[0] = z; p[1] = z;
    } else if (blk == 5128) {
        for (int i = t; i < M_; i += 256) { int tt = i >> 4, b = i & 15; lab_r[i] = labels[b * T_ + tt]; }
    } else {
        for (int i = t; i < 34 * FP_; i += 256) flags[i] = 0;
    }
}

// ---------------- big GEMM + bias: Z[M, 2048] = X[M,512](bf16) @ W1xP + b1 ----------------
__global__ __launch_bounds__(256, 2) void k_gemm_bias(
        const unsigned short* __restrict__ A, const unsigned short* __restrict__ Bp,
        const float* __restrict__ bias, float* __restrict__ C) {
    int bn = blockIdx.x, bm = blockIdx.y;
    int tid = threadIdx.x, lane = tid & 63, w = tid >> 6;
    int wm = w >> 1, wn = w & 1;
    int l15 = lane & 15, quad = lane >> 4;
    floatx4 acc[4][4];
#pragma unroll
    for (int i = 0; i < 4; ++i)
#pragma unroll
        for (int j = 0; j < 4; ++j) acc[i][j] = (floatx4){0.f, 0.f, 0.f, 0.f};
    const unsigned short* Abase = A + (size_t)(bm * 128 + wm * 64 + l15) * KH + quad * 8;
    int ntg0 = bn * 8 + wn * 4;
#pragma unroll 4
    for (int kb = 0; kb < NKB; ++kb) {
        short8 af[4], bf[4];
#pragma unroll
        for (int mt = 0; mt < 4; ++mt) af[mt] = *(const short8*)(Abase + mt * 16 * KH + kb * 32);
#pragma unroll
        for (int nt = 0; nt < 4; ++nt)
            bf[nt] = *(const short8*)(Bp + ((size_t)(ntg0 + nt) * NKB + kb) * 512 + lane * 8);
#pragma unroll
        for (int mt = 0; mt < 4; ++mt)
#pragma unroll
            for (int nt = 0; nt < 4; ++nt)
                acc[mt][nt] = __builtin_amdgcn_mfma_f32_16x16x32_bf16(af[mt], bf[nt], acc[mt][nt], 0, 0, 0);
    }
#pragma unroll
    for (int nt = 0; nt < 4; ++nt) {
        int col = bn * 128 + wn * 64 + nt * 16 + l15;
        float bv = bias[col];
#pragma unroll
        for (int mt = 0; mt < 4; ++mt) {
            int row0 = bm * 128 + wm * 64 + mt * 16 + quad * 4;
#pragma unroll
            for (int r = 0; r < 4; ++r)
                C[(size_t)(row0 + r) * N4H + col] = acc[mt][nt][r] + bv;
        }
    }
}

// ---------------- MEGA persistent kernel ----------------
// 256 blocks x 512 thr, 1 block/CU. Blocks 0..15: L1 recurrence; 16..31: L2; 32..255: logits.
// r9: self-validating tagged h-broadcast. Each h value is a u32 (bf16<<16 | step+1); consumers
// poll the DATA with L2-bypassing dwordx4 loads until tags match — the poll load IS the data
// load. Removes per-step {store-ack, flag store, flag poll, separate data load}: per-step chain
// drops from ~3.5 L3 round trips to ~1.5. L1 blocks need no flags/acks at all; L2 blocks ack +
// post worker-facing flags only every 8th step (bm granularity is all workers need).
// T1 (h1 stream) is full-depth (L2 may lag L1 unboundedly); T2 (h2) is a depth-2 ring (self-loop
// lag provably <=1: a block stores step s only after reading ALL of h2[s-1], which required every
// block's s-1 store, which followed every block's read of h2[s-2]). Streams zeroed each launch.
__global__ __launch_bounds__(512, 2) void k_mega(
        const float* __restrict__ Zpre1, const float* __restrict__ W1,
        const float* __restrict__ W2, const float* __restrict__ b2,
        u32* __restrict__ T1, u32* __restrict__ T2,
        unsigned short* __restrict__ H2, int* __restrict__ flags,
        const float* __restrict__ sw, unsigned short* __restrict__ SWP,
        const float* __restrict__ sb, const int* __restrict__ lab_r,
        float* __restrict__ pm, float* __restrict__ ps, float* __restrict__ labv) {
    const int blk = blockIdx.x, tid = threadIdx.x;
    const int lane = tid & 63, w = tid >> 6;     // 8 waves
    const int l15 = lane & 15, quad = lane >> 4;
    __shared__ unsigned short hs1[16 * HP_];     // staged h (16 rows x 512, pitch 536)
    __shared__ unsigned short hs2[16 * HP_];
    __shared__ float zs[128 * 17];
    u64* H2u = (u64*)H2;

    if (blk < 32) {
        // ================= recurrence =================
        const bool isL2 = blk >= 16;
        const int bj = isL2 ? blk - 16 : blk;
        const int g = w >> 1, half = w & 1;          // gate, col-half
        const int nt = g * 32 + bj * 2 + half;       // n-tile
        const int colg = g * 512 + bj * 32 + half * 16 + l15;

        // register-resident B fragments built directly from fp32 weights
        short8 bfr[32];
        {
            unsigned short vals[8];
            if (!isL2) {
#pragma unroll
                for (int kb = 0; kb < 16; ++kb) {
#pragma unroll
                    for (int j = 0; j < 8; ++j)
                        vals[j] = f2bf(W1[(size_t)(512 + kb * 32 + quad * 8 + j) * N4H + nt * 16 + l15]);
                    bfr[kb] = *(short8*)vals;
                }
            } else {
#pragma unroll
                for (int kb = 0; kb < 32; ++kb) {
#pragma unroll
                    for (int j = 0; j < 8; ++j)
                        vals[j] = f2bf(W2[(size_t)(kb * 32 + quad * 8 + j) * N4H + nt * 16 + l15]);
                    bfr[kb] = *(short8*)vals;
                }
            }
        }
        const float b2c = isL2 ? b2[colg] : 0.f;
        float creg = 0.f;
        const int pu = tid >> 4, pb = tid & 15;      // producer mapping: unit-in-slice, batch
        u32* Tself = isL2 ? T2 : T1;

        for (int s = 0; s < T_; ++s) {
            // ---- Zpre prefetch (L1 only; off critical path, drained by the poll's waitcnt) ----
            float zpre[4];
            if (!isL2) {
#pragma unroll
                for (int r = 0; r < 4; ++r)
                    zpre[r] = Zpre1[(size_t)(s * 16 + quad * 4 + r) * N4H + colg];
            }
            // ---- tagged poll + LDS stage: data arrives WITH the poll ----
            u32 v1[16], v2[16];
            if (!isL2) {
                if (s > 0) {
                    poll16(T1 + (size_t)(s - 1) * 8192 + tid * 16, (u32)s, v1);
                    stage_row(hs1, tid, v1);
                }
            } else {
                if (s == 0) {
                    poll16(T1 + (size_t)tid * 16, 1u, v1);
                    stage_row(hs1, tid, v1);
                } else {
                    poll2(T1 + (size_t)s * 8192 + tid * 16, (u32)(s + 1),
                          T2 + (size_t)((s - 1) & 1) * 8192 + tid * 16, (u32)s, v1, v2);
                    stage_row(hs1, tid, v1);
                    stage_row(hs2, tid, v2);
                }
            }
            __syncthreads();

            // ---- hidden GEMM from LDS frags ----
            if (!isL2) {
                floatx4 a0 = (floatx4){0.f,0.f,0.f,0.f}, a1 = (floatx4){0.f,0.f,0.f,0.f};
                if (s > 0) {
#pragma unroll
                    for (int kb = 0; kb < 8; ++kb) {
                        short8 af = *(const short8*)(&hs1[l15 * HP_ + kb * 32 + quad * 8]);
                        a0 = __builtin_amdgcn_mfma_f32_16x16x32_bf16(af, bfr[kb], a0, 0, 0, 0);
                    }
#pragma unroll
                    for (int kb = 8; kb < 16; ++kb) {
                        short8 af = *(const short8*)(&hs1[l15 * HP_ + kb * 32 + quad * 8]);
                        a1 = __builtin_amdgcn_mfma_f32_16x16x32_bf16(af, bfr[kb], a1, 0, 0, 0);
                    }
                }
                const int zcol = g * 32 + half * 16 + l15;
#pragma unroll
                for (int r = 0; r < 4; ++r)
                    zs[zcol * 17 + quad * 4 + r] = a0[r] + a1[r] + zpre[r];
            } else {
                floatx4 a0 = (floatx4){0.f,0.f,0.f,0.f}, a1 = (floatx4){0.f,0.f,0.f,0.f};
#pragma unroll
                for (int kb = 0; kb < 16; ++kb) {
                    short8 af = *(const short8*)(&hs1[l15 * HP_ + kb * 32 + quad * 8]);
                    a0 = __builtin_amdgcn_mfma_f32_16x16x32_bf16(af, bfr[kb], a0, 0, 0, 0);
                }
                if (s > 0) {
#pragma unroll
                    for (int kb = 0; kb < 16; ++kb) {
                        short8 af = *(const short8*)(&hs2[l15 * HP_ + kb * 32 + quad * 8]);
                        a1 = __builtin_amdgcn_mfma_f32_16x16x32_bf16(af, bfr[16 + kb], a1, 0, 0, 0);
                    }
                }
                const int zcol = g * 32 + half * 16 + l15;
#pragma unroll
                for (int r = 0; r < 4; ++r)
                    zs[zcol * 17 + quad * 4 + r] = a0[r] + a1[r] + b2c;
            }
            __syncthreads();

            // ---- gate math + tagged broadcast (fire-and-forget) ----
            {
                float zi = zs[(0 * 32 + pu) * 17 + pb];
                float zj = zs[(1 * 32 + pu) * 17 + pb];
                float zf = zs[(2 * 32 + pu) * 17 + pb];
                float zo = zs[(3 * 32 + pu) * 17 + pb];
                float si = 1.f / (1.f + __expf(-zi));
                float sf = 1.f / (1.f + __expf(-zf));
                float so = 1.f / (1.f + __expf(-zo));
                float cn = creg * sf + si * tanhf(zj);
                creg = cn;
                unsigned short hbf = f2bf(tanhf(cn) * so);
                u32 tv = ((u32)hbf << 16) | (u32)(s + 1);
                size_t slot = isL2 ? (size_t)(s & 1) * 8192 : (size_t)s * 8192;
                st_ic32(Tself + slot + pb * 512 + bj * 32 + pu, tv);
                if (isL2) {
                    // packed H2 for logits workers (flag-gated plain-cached reads)
                    int hvi = (int)hbf;
                    int lb = lane & 15;
                    unsigned int h0  = (unsigned int)__shfl(hvi, lb);
                    unsigned int h1v = (unsigned int)__shfl(hvi, lb + 16);
                    unsigned int h2v = (unsigned int)__shfl(hvi, lb + 32);
                    unsigned int h3v = (unsigned int)__shfl(hvi, lb + 48);
                    if (lane < 16) {
                        u64 vv = (u64)(h0 | (h1v << 16)) | ((u64)(h2v | (h3v << 16)) << 32);
                        st_ic(H2u + (size_t)(s * 16 + lane) * 128 + bj * 8 + w, vv);
                    }
                }
            }
            // worker-facing ack+flag only every 8th step (bm granularity)
            if (isL2 && ((s & 7) == 7)) {
                __builtin_amdgcn_s_waitcnt(0x0F70);      // vmcnt(0): H2 stores ack'd at IC
                __syncthreads();
                if (tid == 0)
                    __hip_atomic_store(flags + blk * FP_, s + 1, __ATOMIC_RELAXED,
                                       __HIP_MEMORY_SCOPE_AGENT);
            }
        }
    } else {
        // ================= logits workers (unchanged) =================
        const int wid = blk - 32;
        int* wdone = flags + 32 * FP_;

        // ---- phase 0: cooperative SWP pack (st_ic write-through to IC) ----
        for (int t = 0; ; ++t) {
            int c = wid + NWORK * (8 * t + w);
            if (c >= NCHUNK) break;
            int cnt = c >> 4, ckb = c & 15;
            int n = cnt * 16 + l15;
            int kk = ckb * 32 + quad * 8;
            unsigned short vals[8];
            if (n < V_) {
#pragma unroll
                for (int j = 0; j < 8; ++j) vals[j] = f2bf(sw[(size_t)(kk + j) * V_ + n]);
            } else {
#pragma unroll
                for (int j = 0; j < 8; ++j) vals[j] = 0;
            }
            u64 v0 = (u64)vals[0] | ((u64)vals[1] << 16) | ((u64)vals[2] << 32) | ((u64)vals[3] << 48);
            u64 v1 = (u64)vals[4] | ((u64)vals[5] << 16) | ((u64)vals[6] << 32) | ((u64)vals[7] << 48);
            u64* dst = (u64*)(SWP + (size_t)c * 512 + lane * 8);
            st_ic(dst, v0);
            st_ic(dst + 1, v1);
        }
        __builtin_amdgcn_s_waitcnt(0x0F70);          // drain pack stores to IC
        __syncthreads();
        if (tid == 0)
            __hip_atomic_fetch_add(wdone, 1, __ATOMIC_RELAXED, __HIP_MEMORY_SCOPE_AGENT);
        if (w == 0) {
            while (true) {
                int v = (lane == 0)
                    ? __hip_atomic_load(wdone, __ATOMIC_RELAXED, __HIP_MEMORY_SCOPE_AGENT)
                    : 0x7fffffff;
                if (__all(v >= NWORK)) break;
                __builtin_amdgcn_s_sleep(8);
            }
        }
        __syncthreads();

        // ---- phase 1: consume tiles; wave w owns m-strip w (16 rows) x 128 cols ----
        int done_seen = 0;
        for (int k = wid; k < NTILES; k += NWORK) {
            int bm = k / NBLK, bn = k - bm * NBLK;
            int tgt = bm * 8 + 8;            // need H2 rows through t = bm*8+7
            if (tgt > done_seen) {
                if (w == 0) {
                    int* fp = flags + (16 + (lane & 15)) * FP_;
                    while (true) {
                        int v = (lane < 16)
                            ? __hip_atomic_load(fp, __ATOMIC_RELAXED, __HIP_MEMORY_SCOPE_AGENT)
                            : 0x7fffffff;
                        if (__all(v >= tgt)) break;
                        __builtin_amdgcn_s_sleep(8);
                    }
                }
                __syncthreads();
                done_seen = tgt;
            }
            floatx4 acc[8];
#pragma unroll
            for (int j = 0; j < 8; ++j) acc[j] = (floatx4){0.f, 0.f, 0.f, 0.f};
            // A via plain cached 16B loads (flag-gated => coherent-by-construction)
            const short8* Abase = (const short8*)(H2 + (size_t)(bm * 128 + w * 16 + l15) * KH) + quad;
            int ntg0 = bn * 8;
#pragma unroll 4
            for (int kb = 0; kb < NKB; ++kb) {
                short8 af = Abase[kb * 4];
#pragma unroll
                for (int nt = 0; nt < 8; ++nt) {
                    short8 bf = *(const short8*)(SWP + ((size_t)(ntg0 + nt) * NKB + kb) * 512 + lane * 8);
                    acc[nt] = __builtin_amdgcn_mfma_f32_16x16x32_bf16(af, bf, acc[nt], 0, 0, 0);
                }
            }
            // ---- wave-local epilogue ----
            float bv[8]; int colg[8]; bool valid[8];
#pragma unroll
            for (int nt = 0; nt < 8; ++nt) {
                colg[nt] = bn * 128 + nt * 16 + l15;
                valid[nt] = colg[nt] < V_;
                bv[nt] = valid[nt] ? sb[colg[nt]] : 0.f;
            }
#pragma unroll
            for (int r = 0; r < 4; ++r) {
                float m = -3.0e38f;
#pragma unroll
                for (int nt = 0; nt < 8; ++nt) {
                    float v = valid[nt] ? acc[nt][r] + bv[nt] : -3.0e38f;
                    acc[nt][r] = v;
                    m = fmaxf(m, v);
                }
#pragma unroll
                for (int d = 1; d < 16; d <<= 1) m = fmaxf(m, __shfl_xor(m, d, 16));
                float sm = 0.f;
#pragma unroll
                for (int nt = 0; nt < 8; ++nt)
                    if (valid[nt]) sm += __expf(acc[nt][r] - m);
#pragma unroll
                for (int d = 1; d < 16; d <<= 1) sm += __shfl_xor(sm, d, 16);
                int rowg = bm * 128 + w * 16 + quad * 4 + r;
                int lc = lab_r[rowg];
#pragma unroll
                for (int nt = 0; nt < 8; ++nt)
                    if (valid[nt] && colg[nt] == lc) labv[rowg] = acc[nt][r];
                if (l15 == 0) {
                    pm[(size_t)rowg * NBLK + bn] = m;
                    ps[(size_t)rowg * NBLK + bn] = sm;
                }
            }
        }
    }
}

// ---------------- per-row reduction over the 393 tiles ----------------
__global__ void k_rowreduce(const float* __restrict__ pm, const float* __restrict__ ps,
                            const float* __restrict__ labv, float* __restrict__ ll) {
    int row = blockIdx.x;
    int lane = threadIdx.x;  // 64
    const float* pmr = pm + (size_t)row * NBLK;
    const float* psr = ps + (size_t)row * NBLK;
    float m = -3.0e38f;
    for (int j = lane; j < NBLK; j += 64) m = fmaxf(m, pmr[j]);
#pragma unroll
    for (int d = 1; d < 64; d <<= 1) m = fmaxf(m, __shfl_xor(m, d, 64));
    float s = 0.f;
    for (int j = lane; j < NBLK; j += 64) s += psr[j] * __expf(pmr[j] - m);
#pragma unroll
    for (int d = 1; d < 64; d <<= 1) s += __shfl_xor(s, d, 64);
    if (lane == 0) ll[row] = labv[row] - m - logf(s);
}

__global__ void k_final(const float* __restrict__ ll, float* __restrict__ out) {
    int lane = threadIdx.x;  // 64
    float s = 0.f;
    for (int i = lane; i < M_; i += 64) s += ll[i];
#pragma unroll
    for (int d = 1; d < 64; d <<= 1) s += __shfl_xor(s, d, 64);
    if (lane == 0) out[0] = -s / (float)B_;
}

extern "C" void kernel_launch(void* const* d_in, const int* in_sizes, int n_in,
                              void* d_out, int out_size, void* d_ws, size_t ws_size,
                              hipStream_t stream) {
    const int* tokens = (const int*)d_in[0];
    const int* labels = (const int*)d_in[1];
    const float* emb = (const float*)d_in[2];
    const float* W1 = (const float*)d_in[3];
    const float* b1 = (const float*)d_in[4];
    const float* W2 = (const float*)d_in[5];
    const float* b2 = (const float*)d_in[6];
    const float* sw = (const float*)d_in[7];
    const float* sb = (const float*)d_in[8];
    float* out = (float*)d_out;

    char* ws = (char*)d_ws;
    size_t off = 0;
    auto alloc = [&](size_t bytes) {
        void* p = ws + off;
        off = (off + bytes + 255) & ~(size_t)255;
        return p;
    };
    unsigned short* X    = (unsigned short*)alloc((size_t)M_ * KH * 2);
    unsigned short* H2   = (unsigned short*)alloc((size_t)M_ * KH * 2);
    unsigned short* W1xP = (unsigned short*)alloc((size_t)N4H * KH * 2);
    unsigned short* SWP  = (unsigned short*)alloc((size_t)VP_ * KH * 2);
    float* Z     = (float*)alloc((size_t)M_ * N4H * 4);
    u32*   T1    = (u32*)alloc((size_t)T_ * B_ * H_ * 4);     // tagged h1 stream (full depth)
    u32*   T2    = (u32*)alloc((size_t)2 * B_ * H_ * 4);      // tagged h2 ring (depth 2)
    float* pm   = (float*)alloc((size_t)M_ * NBLK * 4);
    float* ps   = (float*)alloc((size_t)M_ * NBLK * 4);
    float* labv = (float*)alloc((size_t)M_ * 4);
    int*   lab_r = (int*)alloc((size_t)M_ * 4);
    float* ll   = (float*)alloc((size_t)M_ * 4);
    int*   flags = (int*)alloc((size_t)34 * FP_ * 4);

    // merged setup: embed + W1x pack + tagged-stream zero + lab_r/flags
    k_setup<<<5130, 256, 0, stream>>>(tokens, labels, emb, W1, X, W1xP, T1, T2, lab_r, flags);

    // layer1 input pre-GEMM: Zpre1 = X @ W1x + b1
    k_gemm_bias<<<dim3(16, 16), 256, 0, stream>>>(X, W1xP, b1, Z);

    // fused persistent recurrence (tagged-poll broadcast) + dataflow logits
    k_mega<<<256, 512, 0, stream>>>(Z, W1, W2, b2, T1, T2, H2, flags,
                                    sw, SWP, sb, lab_r, pm, ps, labv);

    // loss reduction
    k_rowreduce<<<M_, 64, 0, stream>>>(pm, ps, labv, ll);
    k_final<<<1, 64, 0, stream>>>(ll, out);
}